// Round 2
// baseline (30901.202 us; speedup 1.0000x reference)
//
#include <hip/hip_runtime.h>
#include <math.h>

// Problem constants
#define BB  128      // batch
#define NN  400      // spatial locations
#define EE  512      // encoder size
#define SHD 256      // structural hidden
#define HH  512      // cell hidden
#define AA  256      // attention size
#define EMBD 256     // embedding size
#define VV  1000     // vocab
#define TT  256      // timesteps
#define TH3 (3*HH)          // 1536
#define BNROWS (BB*NN)      // 51200
#define PRED_STRIDE (BB*VV) // 128000
#define NPRED ((size_t)TT*BB*VV)

__device__ __forceinline__ float tanh_fast(float x){
    // tanh(x) = 1 - 2/(exp(2x)+1); exact at +/-inf saturation
    float e = __expf(2.f*x);
    return 1.f - 2.f*__builtin_amdgcn_rcpf(e + 1.f);
}

// ---------------- prologue kernels (one-time) ----------------

__global__ void k_zero(float* __restrict__ hbuf0, float* __restrict__ loss_acc){
    int i = blockIdx.x*blockDim.x + threadIdx.x;
    if (i < BB*HH) hbuf0[i] = 0.f;
    if (i == 0) loss_acc[0] = 0.f;
}

// feat_proj[b,n,a] = features[b,n,:] @ Wf[:,a] + bf[a]   (51200x512 @ 512x256)
__global__ __launch_bounds__(256) void k_featproj(
    const float* __restrict__ feats, const float* __restrict__ Wf,
    const float* __restrict__ bf, float* __restrict__ fp)
{
    __shared__ float As[32][65]; // [k][m]
    __shared__ float Bs[32][65]; // [k][n]
    int row0 = blockIdx.x*64, col0 = blockIdx.y*64;
    int tx = threadIdx.x & 15, ty = threadIdx.x >> 4;
    float acc[4][4] = {};
    for (int k0 = 0; k0 < EE; k0 += 32){
        for (int idx = threadIdx.x; idx < 64*32; idx += 256){
            int r = idx >> 5, kk = idx & 31;
            As[kk][r] = feats[(size_t)(row0 + r)*EE + k0 + kk];
        }
        for (int idx = threadIdx.x; idx < 32*64; idx += 256){
            int kk = idx >> 6, c = idx & 63;
            Bs[kk][c] = Wf[(size_t)(k0 + kk)*AA + col0 + c];
        }
        __syncthreads();
        #pragma unroll
        for (int kk = 0; kk < 32; ++kk){
            float a0 = As[kk][ty*4+0], a1 = As[kk][ty*4+1], a2 = As[kk][ty*4+2], a3 = As[kk][ty*4+3];
            float b0 = Bs[kk][tx*4+0], b1 = Bs[kk][tx*4+1], b2 = Bs[kk][tx*4+2], b3 = Bs[kk][tx*4+3];
            acc[0][0] += a0*b0; acc[0][1] += a0*b1; acc[0][2] += a0*b2; acc[0][3] += a0*b3;
            acc[1][0] += a1*b0; acc[1][1] += a1*b1; acc[1][2] += a1*b2; acc[1][3] += a1*b3;
            acc[2][0] += a2*b0; acc[2][1] += a2*b1; acc[2][2] += a2*b2; acc[2][3] += a2*b3;
            acc[3][0] += a3*b0; acc[3][1] += a3*b1; acc[3][2] += a3*b2; acc[3][3] += a3*b3;
        }
        __syncthreads();
    }
    #pragma unroll
    for (int i = 0; i < 4; ++i){
        #pragma unroll
        for (int j = 0; j < 4; ++j){
            int col = col0 + tx*4 + j;
            fp[(size_t)(row0 + ty*4 + i)*AA + col] = acc[i][j] + bf[col];
        }
    }
}

// transpose the EMB part of W_ih:  wT[m, r] = W_ih[r, EE+m]
__global__ void k_wembT(const float* __restrict__ Wih, float* __restrict__ wT){
    int i = blockIdx.x*blockDim.x + threadIdx.x;
    if (i >= EMBD*TH3) return;
    int m = i / TH3, r = i - m*TH3;
    wT[i] = Wih[(size_t)r*(EE+EMBD) + EE + m];
}

// emb_proj[v, r] = emb[v,:] @ W_ih_emb^T + b_ih[r]   (1000x256 @ 256x1536)
__global__ __launch_bounds__(256) void k_embproj(
    const float* __restrict__ emb, const float* __restrict__ wT,
    const float* __restrict__ bih, float* __restrict__ ep)
{
    __shared__ float el[16][257];
    int vt = blockIdx.x, rc = blockIdx.y;
    for (int idx = threadIdx.x; idx < 16*EMBD; idx += 256){
        int v = idx >> 8, m = idx & 255;
        int gv = vt*16 + v;
        el[v][m] = (gv < VV) ? emb[(size_t)gv*EMBD + m] : 0.f;
    }
    __syncthreads();
    int r = rc*256 + threadIdx.x;
    float acc[16] = {};
    for (int m = 0; m < EMBD; ++m){
        float w = wT[(size_t)m*TH3 + r];
        #pragma unroll
        for (int v = 0; v < 16; ++v) acc[v] += el[v][m]*w;
    }
    float bb_ = bih[r];
    #pragma unroll
    for (int v = 0; v < 16; ++v){
        int gv = vt*16 + v;
        if (gv < VV) ep[(size_t)gv*TH3 + r] = acc[v] + bb_;
    }
}

// struct_proj[b,a] = sh[0,b,:] @ Ws[:,a] + bs[a]
__global__ void k_structproj(const float* __restrict__ sh, const float* __restrict__ Ws,
                             const float* __restrict__ bs, float* __restrict__ sp){
    __shared__ float sl[SHD];
    int b = blockIdx.x;
    for (int i = threadIdx.x; i < SHD; i += 256) sl[i] = sh[(size_t)b*SHD + i];
    __syncthreads();
    int a = threadIdx.x;
    float acc = 0.f;
    for (int s = 0; s < SHD; ++s) acc += sl[s]*Ws[(size_t)s*AA + a];
    sp[(size_t)b*AA + a] = acc + bs[a];
}

// ---------------- shared device bodies ----------------

// logits for step tpred: preds[tpred] = h(tpred+1) @ W_fc + b_fc
// NONTEMPORAL stores: preds is 524MB streamed once; keep it out of L3 so the
// hot 157MB (feat_proj + features) stays cache-resident across all 256 steps.
__device__ __forceinline__ void logits_body(int tpred, int bt, int vt,
    const float* __restrict__ hsrc, const float* __restrict__ Wfc,
    const float* __restrict__ bfc, float* __restrict__ preds, float* hl)
{
    for (int idx = threadIdx.x; idx < 8*HH; idx += 512){
        int bl = idx >> 9;
        hl[idx] = hsrc[(size_t)(bt*8+bl)*HH + (idx & 511)];
    }
    __syncthreads();
    for (int o = threadIdx.x; o < 1000; o += 512){
        int bl = o / 125, vl = o - bl*125;
        int v = vt*125 + vl;
        const float* wcol = Wfc + v;
        const float* hrow = hl + bl*HH;
        float acc = 0.f;
        #pragma unroll 4
        for (int h = 0; h < HH; ++h) acc += hrow[h]*wcol[(size_t)h*VV];
        __builtin_nontemporal_store(acc + bfc[v],
            &preds[(size_t)tpred*PRED_STRIDE + (size_t)(bt*8+bl)*VV + v]);
    }
}

// loss for step tpred over rows [lb*16, lb*16+16)
__device__ __forceinline__ void loss_body(int tpred, int lb,
    const float* __restrict__ preds, const int* __restrict__ tgt, float* loss_acc)
{
    int w = threadIdx.x >> 6, lane = threadIdx.x & 63;
    float contrib = 0.f;
    for (int rr = 0; rr < 2; ++rr){
        int row = lb*16 + w*2 + rr;
        const float* p = preds + (size_t)tpred*PRED_STRIDE + (size_t)row*VV;
        float m = -1e30f;
        for (int i = lane; i < VV; i += 64) m = fmaxf(m, __builtin_nontemporal_load(p + i));
        #pragma unroll
        for (int off = 32; off; off >>= 1) m = fmaxf(m, __shfl_xor(m, off));
        float s = 0.f;
        for (int i = lane; i < VV; i += 64) s += expf(__builtin_nontemporal_load(p + i) - m);
        #pragma unroll
        for (int off = 32; off; off >>= 1) s += __shfl_xor(s, off);
        if (lane == 0) contrib += m + logf(s) - p[tgt[(size_t)row*TT + tpred]];
    }
    if (lane == 0) atomicAdd(loss_acc, contrib);
}

// ---------------- per-step kernel 1: attention (+ logits(t-1)) ----------------
// blocks 0..255 : (b, half-of-N) attention partials
// blocks 256..383: logits for step t-1 (skipped at t==0)
__global__ __launch_bounds__(512) void k_attn(int t,
    const float* __restrict__ fp, const float* __restrict__ feats,
    const float* __restrict__ sp, const float* __restrict__ bc,
    const float* __restrict__ vatt, const float* __restrict__ qpart,
    const float* __restrict__ hin, const float* __restrict__ Wfc,
    const float* __restrict__ bfc,
    float* __restrict__ pctx, float* __restrict__ psum, float* __restrict__ preds)
{
    __shared__ __align__(16) float smem[AA + 8*EE + 8];
    if (blockIdx.x >= 256){
        if (t == 0) return;
        int lb = blockIdx.x - 256;
        logits_body(t-1, lb >> 3, lb & 7, hin, Wfc, bfc, preds, smem);
        return;
    }
    int b = blockIdx.x >> 1, half = blockIdx.x & 1;
    float* qs = smem;              // [256]
    float* px = smem + AA;         // [8][512]
    float* ps = smem + AA + 8*EE;  // [8]
    // q(t) = struct_proj + bc (+ sum of 32 partial h@Wc slices from previous k_gru)
    if (threadIdx.x < AA){
        int a = threadIdx.x;
        float val = sp[(size_t)b*AA + a] + bc[a];
        if (t > 0){
            #pragma unroll 4
            for (int jt = 0; jt < 32; ++jt) val += qpart[((size_t)jt*BB + b)*AA + a];
        }
        qs[a] = val;
    }
    __syncthreads();
    int w = threadIdx.x >> 6, lane = threadIdx.x & 63;
    float4 v4 = ((const float4*)vatt)[lane];
    float4 q4 = ((const float4*)qs)[lane];
    float acc0=0,acc1=0,acc2=0,acc3=0,acc4=0,acc5=0,acc6=0,acc7=0;
    float psum_r = 0.f;
    const int nbase = half*200;
    for (int k = 0; k < 25; ++k){
        int n = nbase + w + 8*k;
        const float4* fr4 = (const float4*)(fp + ((size_t)b*NN + n)*AA);
        float4 xv = fr4[lane];
        float s = v4.x*tanh_fast(xv.x+q4.x) + v4.y*tanh_fast(xv.y+q4.y)
                + v4.z*tanh_fast(xv.z+q4.z) + v4.w*tanh_fast(xv.w+q4.w);
        #pragma unroll
        for (int off = 32; off; off >>= 1) s += __shfl_xor(s, off);
        float e = __expf(s);    // no max-subtract: |s| <= sum|v| ~ 10, exp safe in f32
        psum_r += e;
        const float4* f4 = (const float4*)(feats + ((size_t)b*NN + n)*EE) + lane*2;
        float4 fa = f4[0], fb = f4[1];
        acc0 += e*fa.x; acc1 += e*fa.y; acc2 += e*fa.z; acc3 += e*fa.w;
        acc4 += e*fb.x; acc5 += e*fb.y; acc6 += e*fb.z; acc7 += e*fb.w;
    }
    float* myrow = px + w*EE + lane*8;
    myrow[0]=acc0; myrow[1]=acc1; myrow[2]=acc2; myrow[3]=acc3;
    myrow[4]=acc4; myrow[5]=acc5; myrow[6]=acc6; myrow[7]=acc7;
    if (lane == 0) ps[w] = psum_r;
    __syncthreads();
    for (int e = threadIdx.x; e < EE; e += 512){
        float tot = 0.f;
        #pragma unroll
        for (int ww = 0; ww < 8; ++ww) tot += px[ww*EE + e];
        pctx[((size_t)b*2 + half)*EE + e] = tot;
    }
    if (threadIdx.x == 0){
        float tot = 0.f;
        #pragma unroll
        for (int ww = 0; ww < 8; ++ww) tot += ps[ww];
        psum[b*2 + half] = tot;
    }
}

// ---------------- per-step kernel 2: GRU (+ q-partials, + loss(t-1)) ----------------
// blocks 0..255 : (b_tile=16) x (j_tile=16 of H) GRU update + qpart contribution
// blocks 256..263: loss for step t-1 (skipped at t==0)
__global__ __launch_bounds__(512) void k_gru(int t,
    const float* __restrict__ pctx, const float* __restrict__ psum,
    const float* __restrict__ hin, float* __restrict__ hout,
    const float* __restrict__ Wih, const float* __restrict__ Whh,
    const float* __restrict__ bhh, const float* __restrict__ embp,
    const int* __restrict__ tgt, const float* __restrict__ Wc,
    float* __restrict__ qpart, const float* __restrict__ preds,
    float* __restrict__ loss_acc)
{
    if (blockIdx.x >= 256){
        if (t == 0) return;
        loss_body(t-1, (int)blockIdx.x - 256, preds, tgt, loss_acc);
        return;
    }
    __shared__ __align__(16) float stage[16][516]; // ctx then h (time-shared)
    __shared__ float part[2][16][16][3];
    __shared__ float gi_s[16][16][3];
    __shared__ float hn_l[16][16];
    __shared__ float inv_l[16];
    int bt = blockIdx.x >> 5, jt = blockIdx.x & 31;
    int bg = bt*16, jbase = jt*16;
    int p = threadIdx.x & 255, role = threadIdx.x >> 8;
    int b = p & 15, j = p >> 4, r0 = jbase + j;
    // combine softmax partials -> context, stage into LDS
    if (threadIdx.x < 16){
        int bb_ = threadIdx.x;
        inv_l[bb_] = 1.f/(psum[(bg+bb_)*2] + psum[(bg+bb_)*2+1]);
    }
    __syncthreads();
    for (int idx = threadIdx.x; idx < 16*EE; idx += 512){
        int bb_ = idx >> 9, e = idx & 511;
        stage[bb_][e] = (pctx[((size_t)(bg+bb_)*2)*EE + e] +
                         pctx[((size_t)(bg+bb_)*2+1)*EE + e]) * inv_l[bb_];
    }
    __syncthreads();
    // gi partial dots (ctx part of W_ih), role splits the e range
    {
        const float* w0 = Wih + (size_t)r0*(EE+EMBD);
        const float* w1 = w0 + (size_t)512*(EE+EMBD);
        const float* w2 = w0 + (size_t)1024*(EE+EMBD);
        float ar=0, az=0, an=0;
        int e0 = role*256;
        const float4* srow = (const float4*)&stage[b][0];
        #pragma unroll 4
        for (int e4 = e0/4; e4 < e0/4 + 64; ++e4){
            float4 c = srow[e4];
            int e = e4*4;
            ar += c.x*w0[e] + c.y*w0[e+1] + c.z*w0[e+2] + c.w*w0[e+3];
            az += c.x*w1[e] + c.y*w1[e+1] + c.z*w1[e+2] + c.w*w1[e+3];
            an += c.x*w2[e] + c.y*w2[e+1] + c.z*w2[e+2] + c.w*w2[e+3];
        }
        part[role][b][j][0] = ar; part[role][b][j][1] = az; part[role][b][j][2] = an;
    }
    __syncthreads();
    // restage h; combine gi (+ precomputed embedding projection incl. b_ih)
    if (threadIdx.x < 256){
        int tok = (t == 0) ? 0 : tgt[(size_t)(bg+b)*TT + (t-1)];
        const float* er = embp + (size_t)tok*TH3 + r0;
        gi_s[b][j][0] = part[0][b][j][0] + part[1][b][j][0] + er[0];
        gi_s[b][j][1] = part[0][b][j][1] + part[1][b][j][1] + er[512];
        gi_s[b][j][2] = part[0][b][j][2] + part[1][b][j][2] + er[1024];
    }
    __syncthreads();   // gi combine done reading part; stage free
    for (int idx = threadIdx.x; idx < 16*HH; idx += 512){
        int bb_ = idx >> 9, e = idx & 511;
        stage[bb_][e] = hin[(size_t)(bg+bb_)*HH + e];
    }
    __syncthreads();
    // gh partial dots
    {
        const float* w0 = Whh + (size_t)r0*HH;
        const float* w1 = w0 + (size_t)512*HH;
        const float* w2 = w0 + (size_t)1024*HH;
        float ar=0, az=0, an=0;
        int e0 = role*256;
        const float4* srow = (const float4*)&stage[b][0];
        #pragma unroll 4
        for (int e4 = e0/4; e4 < e0/4 + 64; ++e4){
            float4 c = srow[e4];
            int e = e4*4;
            ar += c.x*w0[e] + c.y*w0[e+1] + c.z*w0[e+2] + c.w*w0[e+3];
            az += c.x*w1[e] + c.y*w1[e+1] + c.z*w1[e+2] + c.w*w1[e+3];
            an += c.x*w2[e] + c.y*w2[e+1] + c.z*w2[e+2] + c.w*w2[e+3];
        }
        part[role][b][j][0] = ar; part[role][b][j][1] = az; part[role][b][j][2] = an;
    }
    __syncthreads();
    // gates + h_new
    if (threadIdx.x < 256){
        float ghr = part[0][b][j][0] + part[1][b][j][0] + bhh[r0];
        float ghz = part[0][b][j][1] + part[1][b][j][1] + bhh[r0+512];
        float ghn = part[0][b][j][2] + part[1][b][j][2] + bhh[r0+1024];
        float rr = 1.f/(1.f + expf(-(gi_s[b][j][0] + ghr)));
        float zz = 1.f/(1.f + expf(-(gi_s[b][j][1] + ghz)));
        float nn = tanhf(gi_s[b][j][2] + rr*ghn);
        float hval = stage[b][r0];
        float hn = (1.f - zz)*nn + zz*hval;
        hout[(size_t)(bg+b)*HH + r0] = hn;
        hn_l[b][j] = hn;
    }
    __syncthreads();
    // q(t+1) partial: qpart[jt][b][a] = sum_{j in tile} h_new[b, jbase+j] * Wc[jbase+j, a]
    for (int o = threadIdx.x; o < 16*AA; o += 512){
        int bb_ = o >> 8, a = o & 255;
        float acc = 0.f;
        #pragma unroll
        for (int jj = 0; jj < 16; ++jj) acc += hn_l[bb_][jj]*Wc[(size_t)(jbase+jj)*AA + a];
        qpart[((size_t)jt*BB + bg + bb_)*AA + a] = acc;
    }
}

// ---------------- epilogue ----------------
__global__ __launch_bounds__(512) void k_logits_ep(int tpred, const float* __restrict__ hsrc,
    const float* __restrict__ Wfc, const float* __restrict__ bfc, float* __restrict__ preds)
{
    __shared__ __align__(16) float hl[8*HH];
    logits_body(tpred, (int)blockIdx.x >> 3, (int)blockIdx.x & 7, hsrc, Wfc, bfc, preds, hl);
}

__global__ __launch_bounds__(512) void k_loss_ep(int tpred, const float* __restrict__ preds,
    const int* __restrict__ tgt, float* __restrict__ loss_acc)
{
    loss_body(tpred, (int)blockIdx.x, preds, tgt, loss_acc);
}

__global__ void k_final(const float* __restrict__ loss_acc, float* __restrict__ out){
    // losses.sum()/T/B where each loss_t already has 1/B  ->  / (T*B*B)
    out[0] = loss_acc[0] * (1.f/4194304.f);
}

// ---------------- host ----------------
extern "C" void kernel_launch(void* const* d_in, const int* in_sizes, int n_in,
                              void* d_out, int out_size, void* d_ws, size_t ws_size,
                              hipStream_t stream)
{
    const float* feats = (const float*)d_in[0];
    const float* shs   = (const float*)d_in[1];
    const int*   tgt   = (const int*)d_in[2];
    const float* Wf    = (const float*)d_in[3];
    const float* bf    = (const float*)d_in[4];
    const float* Ws    = (const float*)d_in[5];
    const float* bs    = (const float*)d_in[6];
    const float* Wc    = (const float*)d_in[7];
    const float* bc    = (const float*)d_in[8];
    const float* vatt  = (const float*)d_in[9];
    const float* emb   = (const float*)d_in[10];
    const float* Wih   = (const float*)d_in[11];
    const float* Whh   = (const float*)d_in[12];
    const float* bih   = (const float*)d_in[13];
    const float* bhh   = (const float*)d_in[14];
    const float* Wfc   = (const float*)d_in[15];
    const float* bfc   = (const float*)d_in[16];
    float* preds = (float*)d_out;

    char* base = (char*)d_ws;
    size_t off = 0;
    auto alloc = [&](size_t nfloats) -> float* {
        float* ptr = (float*)(base + off);
        off += ((nfloats*sizeof(float) + 255)/256)*256;
        return ptr;
    };
    float* fp    = alloc((size_t)BNROWS*AA);   // 13.1M  feat_proj
    float* embp  = alloc((size_t)VV*TH3);      // 1.54M  emb@W_ih_emb^T + b_ih
    float* wT    = alloc((size_t)EMBD*TH3);    // 0.39M
    float* sp    = alloc((size_t)BB*AA);       // struct_proj + bs
    float* qpart = alloc((size_t)32*BB*AA);    // 32 j-tile partials of h@Wc
    float* pctx  = alloc((size_t)BB*2*EE);     // unnormalized context halves
    float* psum  = alloc((size_t)BB*2);        // exp-sum halves
    float* hbuf  = alloc((size_t)2*BB*HH);     // double-buffered h
    float* lacc  = alloc(16);                  // loss accumulator
    (void)ws_size; (void)in_sizes; (void)n_in; (void)out_size;

    k_zero<<<(BB*HH + 511)/512, 512, 0, stream>>>(hbuf, lacc);
    k_featproj<<<dim3(BNROWS/64, AA/64), 256, 0, stream>>>(feats, Wf, bf, fp);
    k_wembT<<<(EMBD*TH3)/256, 256, 0, stream>>>(Wih, wT);
    k_embproj<<<dim3(63, TH3/256), 256, 0, stream>>>(emb, wT, bih, embp);
    k_structproj<<<BB, 256, 0, stream>>>(shs, Ws, bs, sp);

    for (int t = 0; t < TT; ++t){
        const float* hin = hbuf + (size_t)(t & 1)*BB*HH;
        float*       hout = hbuf + (size_t)((t + 1) & 1)*BB*HH;
        k_attn<<<384, 512, 0, stream>>>(t, fp, feats, sp, bc, vatt, qpart,
                                        hin, Wfc, bfc, pctx, psum, preds);
        k_gru<<<264, 512, 0, stream>>>(t, pctx, psum, hin, hout, Wih, Whh, bhh,
                                       embp, tgt, Wc, qpart, preds, lacc);
    }
    // logits + loss for the final step (h(256) lives in buffer 0), then finalize
    k_logits_ep<<<128, 512, 0, stream>>>(TT-1, hbuf, Wfc, bfc, preds);
    k_loss_ep<<<8, 512, 0, stream>>>(TT-1, preds, tgt, lacc);
    k_final<<<1, 1, 0, stream>>>(lacc, preds + NPRED);
}